// Round 1
// baseline (550.807 us; speedup 1.0000x reference)
//
#include <hip/hip_runtime.h>
#include <stdint.h>

// ---------------------------------------------------------------------------
// Batched NT GEMM: C[b][i][j] = sum_k A[b][i][k] * B[b][j][k]
// B=8, M=N=4096, K=128. fp32 in/out. Strategy: cast to bf16 (threshold 1.38
// allows ~0.3 absmax), MFMA 16x16x32_bf16, m97-style 128x128 tile with
// global_load_lds width-16 staging. Output-write bound (~537 MB HBM writes).
// ---------------------------------------------------------------------------

#define M_DIM 4096
#define N_DIM 4096
#define K_DIM 128

typedef __bf16  bf16x8 __attribute__((ext_vector_type(8)));
typedef float   f32x4  __attribute__((ext_vector_type(4)));

__device__ static inline unsigned short f2bf(float x) {
  union { float f; unsigned int u; } v; v.f = x;
  unsigned int u = v.u;
  unsigned int r = u + 0x7fffu + ((u >> 16) & 1u);   // RNE
  return (unsigned short)(r >> 16);
}

// fp32 -> bf16 conversion, 8 elements/thread (2x float4 in, 16B out)
__global__ __launch_bounds__(256) void cvt_kernel(const float* __restrict__ in,
                                                  unsigned short* __restrict__ out,
                                                  int n /* elements, multiple of 8 */) {
  int i = blockIdx.x * 256 + threadIdx.x;
  int n8 = n >> 3;
  if (i >= n8) return;
  const float4* p = (const float4*)in;
  float4 a = p[2 * i];
  float4 b = p[2 * i + 1];
  uint4 o;
  o.x = (unsigned)f2bf(a.x) | ((unsigned)f2bf(a.y) << 16);
  o.y = (unsigned)f2bf(a.z) | ((unsigned)f2bf(a.w) << 16);
  o.z = (unsigned)f2bf(b.x) | ((unsigned)f2bf(b.y) << 16);
  o.w = (unsigned)f2bf(b.z) | ((unsigned)f2bf(b.w) << 16);
  ((uint4*)out)[i] = o;
}

// async 16B global -> LDS copy. LDS dest must be wave-uniform base + lane*16
// (we guarantee this: lds offset = (t*256 + wid*64 + lane)*16).
__device__ static inline void gl_lds16(const void* g, void* l) {
  __builtin_amdgcn_global_load_lds(
      (const __attribute__((address_space(1))) unsigned int*)g,
      (__attribute__((address_space(3))) unsigned int*)l,
      16, 0, 0);
}

// 128x128 tile, BK=32, 4 waves (2x2), each wave 64x64 = 4x4 MFMA 16x16x32.
__global__ __launch_bounds__(256) void gemm_bt_bf16(const unsigned short* __restrict__ A,
                                                    const unsigned short* __restrict__ Bm,
                                                    float* __restrict__ C) {
  // UNPADDED row-major [row][32] bf16 tiles — required by global_load_lds
  // (contiguous in lane order); row stride 64 B.
  __shared__ unsigned short As[128 * 32];
  __shared__ unsigned short Bs[128 * 32];

  const int tid  = threadIdx.x;
  const int lane = tid & 63;
  const int wid  = tid >> 6;
  const int wm   = wid >> 1;          // wave row (0..1)
  const int wn   = wid & 1;           // wave col (0..1)

  const int bz = blockIdx.z;
  const int bm = blockIdx.y * 128;
  const int bn = blockIdx.x * 128;

  const unsigned short* Ab = A  + (size_t)bz * M_DIM * K_DIM;
  const unsigned short* Bb = Bm + (size_t)bz * N_DIM * K_DIM;
  float*                Cb = C  + (size_t)bz * M_DIM * N_DIM;

  f32x4 acc[4][4] = {};

  const int mrow = lane & 15;         // row within 16-tile (A) / col row (B)
  const int kg   = lane >> 4;         // k-group 0..3, 8 bf16 each

  for (int k0 = 0; k0 < K_DIM; k0 += 32) {
    // ---- stage A,B tiles: 512 chunks of 16B each, 2 per thread per matrix
    #pragma unroll
    for (int t = 0; t < 2; ++t) {
      int chunk = t * 256 + tid;      // 0..511
      int row   = chunk >> 2;         // tile row 0..127
      int q     = chunk & 3;          // 16B quad within the 64B row segment
      gl_lds16(Ab + (size_t)(bm + row) * K_DIM + k0 + q * 8, (char*)As + chunk * 16);
      gl_lds16(Bb + (size_t)(bn + row) * K_DIM + k0 + q * 8, (char*)Bs + chunk * 16);
    }
    __syncthreads();   // compiler drains vmcnt before s_barrier

    // ---- fragments: lane holds 8 contiguous k at row (lane&15), kg*8
    bf16x8 af[4], bfr[4];
    #pragma unroll
    for (int mi = 0; mi < 4; ++mi)
      af[mi] = *(const bf16x8*)&As[(wm * 64 + mi * 16 + mrow) * 32 + kg * 8];
    #pragma unroll
    for (int ni = 0; ni < 4; ++ni)
      bfr[ni] = *(const bf16x8*)&Bs[(wn * 64 + ni * 16 + mrow) * 32 + kg * 8];

    #pragma unroll
    for (int mi = 0; mi < 4; ++mi)
      #pragma unroll
      for (int ni = 0; ni < 4; ++ni)
        acc[mi][ni] = __builtin_amdgcn_mfma_f32_16x16x32_bf16(af[mi], bfr[ni],
                                                              acc[mi][ni], 0, 0, 0);
    __syncthreads();
  }

  // ---- epilogue: C/D layout col=lane&15, row=(lane>>4)*4+reg  [m89/m91]
  const int rbase = (lane >> 4) * 4;
  const int col   = lane & 15;
  #pragma unroll
  for (int mi = 0; mi < 4; ++mi) {
    #pragma unroll
    for (int ni = 0; ni < 4; ++ni) {
      int gr = bm + wm * 64 + mi * 16 + rbase;
      int gc = bn + wn * 64 + ni * 16 + col;
      float* cp = Cb + (size_t)gr * N_DIM + gc;
      #pragma unroll
      for (int t = 0; t < 4; ++t)
        cp[(size_t)t * N_DIM] = acc[mi][ni][t];
    }
  }
}

// Insurance path if ws_size is too small for bf16 copies: fp32 vector GEMM.
__global__ void gemm_f32_fallback(const float* __restrict__ A,
                                  const float* __restrict__ B,
                                  float* __restrict__ C) {
  __shared__ float As[16][128];
  __shared__ float Bs2[16][128];
  int tx = threadIdx.x, ty = threadIdx.y;
  int tid = ty * 16 + tx;
  int bz = blockIdx.z;
  int bm = blockIdx.y * 16, bn = blockIdx.x * 16;
  const float* Ab = A + (size_t)bz * M_DIM * K_DIM;
  const float* Bb = B + (size_t)bz * N_DIM * K_DIM;
  for (int i = tid; i < 16 * 128; i += 256) {
    int r = i >> 7, c = i & 127;
    As[r][c]  = Ab[(size_t)(bm + r) * K_DIM + c];
    Bs2[r][c] = Bb[(size_t)(bn + r) * K_DIM + c];
  }
  __syncthreads();
  float s = 0.f;
  #pragma unroll 8
  for (int k = 0; k < 128; ++k) s += As[ty][k] * Bs2[tx][k];
  C[(size_t)bz * M_DIM * N_DIM + (size_t)(bm + ty) * N_DIM + bn + tx] = s;
}

extern "C" void kernel_launch(void* const* d_in, const int* in_sizes, int n_in,
                              void* d_out, int out_size, void* d_ws, size_t ws_size,
                              hipStream_t stream) {
  const float* A  = (const float*)d_in[0];
  const float* Bm = (const float*)d_in[1];
  float*       C  = (float*)d_out;

  const size_t elems    = (size_t)8 * M_DIM * K_DIM;   // 4,194,304 per matrix
  const size_t bf_bytes = elems * 2;                   // 8,388,608 B

  if (ws_size >= 2 * bf_bytes) {
    unsigned short* Abf = (unsigned short*)d_ws;
    unsigned short* Bbf = (unsigned short*)((char*)d_ws + bf_bytes);
    int n8 = (int)(elems >> 3);                        // 524,288 threads
    cvt_kernel<<<(n8 + 255) / 256, 256, 0, stream>>>(A,  Abf, (int)elems);
    cvt_kernel<<<(n8 + 255) / 256, 256, 0, stream>>>(Bm, Bbf, (int)elems);
    dim3 grid(N_DIM / 128, M_DIM / 128, 8);            // 32 x 32 x 8
    gemm_bt_bf16<<<grid, 256, 0, stream>>>(Abf, Bbf, C);
  } else {
    dim3 grid(N_DIM / 16, M_DIM / 16, 8);
    gemm_f32_fallback<<<grid, dim3(16, 16), 0, stream>>>(A, Bm, C);
  }
}